// Round 2
// baseline (503.756 us; speedup 1.0000x reference)
//
#include <hip/hip_runtime.h>
#include <hip/hip_bf16.h>

#define T_STEPS 512
#define BATCH 32
#define NST 64
#define DIM 1024

// ---------------- Projection GEMM ----------------
// proj[m][g*64+n] = dot(x[m][:], W_g[n][:]),  m in [0,16384), g = blockIdx.y.
// Tile 128(m) x 64(n), BK=16, 128 threads, 8x8 outputs/thread.
// LDS k-major, strides 132/68 floats: 16B-aligned rows, <=2-way write conflicts (free).
__global__ __launch_bounds__(128) void proj_gemm(
    const float* __restrict__ x, const float* __restrict__ Wk,
    const float* __restrict__ Wv, const float* __restrict__ Wq,
    const float* __restrict__ Wa, float* __restrict__ proj) {
  const int g = blockIdx.y;
  const float* W = (g == 0) ? Wk : (g == 1) ? Wv : (g == 2) ? Wq : Wa;
  const int bm0 = blockIdx.x * 128;
  const int tid = threadIdx.x;
  const int tm = tid >> 3;   // 0..15 -> 8 rows each
  const int tn = tid & 7;    // 0..7  -> 8 cols each

  __shared__ __align__(16) float xs[16][132];
  __shared__ __align__(16) float ws[16][68];

  float acc[8][8];
#pragma unroll
  for (int a = 0; a < 8; ++a)
#pragma unroll
    for (int bq = 0; bq < 8; ++bq) acc[a][bq] = 0.f;

  float4 xr[4];
  float4 wr[2];
  // staging: x tile 512 float4 (4/thread), W tile 256 float4 (2/thread)
#define LOAD_TILE(k0)                                                    \
  {                                                                      \
    _Pragma("unroll") for (int r = 0; r < 4; ++r) {                      \
      int idx = tid + r * 128; int m = idx >> 2, k4 = (idx & 3) << 2;    \
      xr[r] = *(const float4*)(x + (size_t)(bm0 + m) * DIM + (k0) + k4); \
    }                                                                    \
    _Pragma("unroll") for (int r = 0; r < 2; ++r) {                      \
      int idx = tid + r * 128; int m = idx >> 2, k4 = (idx & 3) << 2;    \
      wr[r] = *(const float4*)(W + (size_t)m * DIM + (k0) + k4);         \
    }                                                                    \
  }

  LOAD_TILE(0);
  for (int k0 = 0; k0 < DIM; k0 += 16) {
    __syncthreads();  // previous tile's LDS reads complete
#pragma unroll
    for (int r = 0; r < 4; ++r) {
      int idx = tid + r * 128; int m = idx >> 2, k4 = (idx & 3) << 2;
      xs[k4 + 0][m] = xr[r].x; xs[k4 + 1][m] = xr[r].y;
      xs[k4 + 2][m] = xr[r].z; xs[k4 + 3][m] = xr[r].w;
    }
#pragma unroll
    for (int r = 0; r < 2; ++r) {
      int idx = tid + r * 128; int m = idx >> 2, k4 = (idx & 3) << 2;
      ws[k4 + 0][m] = wr[r].x; ws[k4 + 1][m] = wr[r].y;
      ws[k4 + 2][m] = wr[r].z; ws[k4 + 3][m] = wr[r].w;
    }
    __syncthreads();
    if (k0 + 16 < DIM) LOAD_TILE(k0 + 16);  // prefetch next tile during compute
#pragma unroll
    for (int kk = 0; kk < 16; ++kk) {
      float av[8], bv[8];
      *(float4*)&av[0] = *(const float4*)&xs[kk][tm * 8];
      *(float4*)&av[4] = *(const float4*)&xs[kk][tm * 8 + 4];
      *(float4*)&bv[0] = *(const float4*)&ws[kk][tn * 8];
      *(float4*)&bv[4] = *(const float4*)&ws[kk][tn * 8 + 4];
#pragma unroll
      for (int mi = 0; mi < 8; ++mi)
#pragma unroll
        for (int ni = 0; ni < 8; ++ni)
          acc[mi][ni] = fmaf(av[mi], bv[ni], acc[mi][ni]);
    }
  }
#undef LOAD_TILE

#pragma unroll
  for (int mi = 0; mi < 8; ++mi) {
    float* o = proj + (size_t)(bm0 + tm * 8 + mi) * 256 + g * 64 + tn * 8;
    float4 o0 = {acc[mi][0], acc[mi][1], acc[mi][2], acc[mi][3]};
    float4 o1 = {acc[mi][4], acc[mi][5], acc[mi][6], acc[mi][7]};
    *(float4*)o = o0;
    *(float4*)(o + 4) = o1;
  }
}

// ---------------- Sequential scan (barrier-free) ----------------
// 64 blocks x 256 threads. Block = (batch b, half): rows i = half*32 + (tid>>3).
// Thread (i, jc=tid&7) owns S[b][i][jc*8 .. jc*8+7] in registers.
// Cross-thread comm only within the 8-lane row group (same wave) via shfl_xor.
// proj read directly from global (L1 broadcast), register-pipelined 2 steps deep.
__global__ __launch_bounds__(256) void scan_kernel(
    const float* __restrict__ proj, const float* __restrict__ S0,
    const float* __restrict__ d_alpha, const float* __restrict__ b_alpha,
    float* __restrict__ out, float* __restrict__ Sout) {
  const int blk = blockIdx.x;
  const int b = blk >> 1;
  const int half = blk & 1;
  const int tid = threadIdx.x;
  const int i = half * 32 + (tid >> 3);
  const int jc = tid & 7;
  const int j0 = jc << 3;

  float s[8];
  {
    float4 v0 = *(const float4*)(S0 + ((size_t)b * NST + i) * NST + j0);
    float4 v1 = *(const float4*)(S0 + ((size_t)b * NST + i) * NST + j0 + 4);
    s[0] = v0.x; s[1] = v0.y; s[2] = v0.z; s[3] = v0.w;
    s[4] = v1.x; s[5] = v1.y; s[6] = v1.z; s[7] = v1.w;
  }
  const float da = d_alpha[i];
  const float ba = b_alpha[i];

  const float* pb = proj + (size_t)b * 256;  // step stride = 32*256 floats

  float4 ks0[2], ks1[2], qs0[2], qs1[2];
  float vs[2], as[2];
#define LD_STEP(t, p)                                   \
  {                                                     \
    const float* P = pb + (size_t)(t) * (BATCH * 256);  \
    ks0[p] = *(const float4*)(P + j0);                  \
    ks1[p] = *(const float4*)(P + j0 + 4);              \
    qs0[p] = *(const float4*)(P + 128 + j0);            \
    qs1[p] = *(const float4*)(P + 128 + j0 + 4);        \
    vs[p] = P[64 + i];                                  \
    as[p] = P[192 + i];                                 \
  }

  LD_STEP(0, 0);
  LD_STEP(1, 1);

#pragma unroll 2
  for (int t = 0; t < T_STEPS; ++t) {
    const int p = t & 1;
    float kv[8], qv[8];
    kv[0] = ks0[p].x; kv[1] = ks0[p].y; kv[2] = ks0[p].z; kv[3] = ks0[p].w;
    kv[4] = ks1[p].x; kv[5] = ks1[p].y; kv[6] = ks1[p].z; kv[7] = ks1[p].w;
    qv[0] = qs0[p].x; qv[1] = qs0[p].y; qv[2] = qs0[p].z; qv[3] = qs0[p].w;
    qv[4] = qs1[p].x; qv[5] = qs1[p].y; qv[6] = qs1[p].z; qv[7] = qs1[p].w;
    const float vi = vs[p];
    const float axi = as[p];
    if (t + 2 < T_STEPS) LD_STEP(t + 2, p);  // prefetch 2 ahead

    // retrieved_i = S[i,:] . k   (partial over 8 owned elems, reduce over 8 lanes)
    float p0 = fmaf(s[0], kv[0], s[4] * kv[4]);
    float p1 = fmaf(s[1], kv[1], s[5] * kv[5]);
    float p2 = fmaf(s[2], kv[2], s[6] * kv[6]);
    float p3 = fmaf(s[3], kv[3], s[7] * kv[7]);
    float rr = (p0 + p1) + (p2 + p3);
    rr += __shfl_xor(rr, 1);
    rr += __shfl_xor(rr, 2);
    rr += __shfl_xor(rr, 4);

    // alpha = 1/(1+e), e = exp(-(ax + da*rr + ba)); c = (1-alpha)*v = e*v*alpha
    const float z = fmaf(da, rr, axi + ba);
    const float e = __expf(-z);
    const float alpha = __builtin_amdgcn_rcpf(1.0f + e);
    const float c = (e * vi) * alpha;

    // S update + h = S_new[i,:] . q
    float h0 = 0.f, h1 = 0.f, h2 = 0.f, h3 = 0.f;
#pragma unroll
    for (int r = 0; r < 2; ++r) {
      s[r * 4 + 0] = fmaf(alpha, s[r * 4 + 0], c * kv[r * 4 + 0]);
      s[r * 4 + 1] = fmaf(alpha, s[r * 4 + 1], c * kv[r * 4 + 1]);
      s[r * 4 + 2] = fmaf(alpha, s[r * 4 + 2], c * kv[r * 4 + 2]);
      s[r * 4 + 3] = fmaf(alpha, s[r * 4 + 3], c * kv[r * 4 + 3]);
      h0 = fmaf(s[r * 4 + 0], qv[r * 4 + 0], h0);
      h1 = fmaf(s[r * 4 + 1], qv[r * 4 + 1], h1);
      h2 = fmaf(s[r * 4 + 2], qv[r * 4 + 2], h2);
      h3 = fmaf(s[r * 4 + 3], qv[r * 4 + 3], h3);
    }
    float h = (h0 + h1) + (h2 + h3);
    h += __shfl_xor(h, 1);
    h += __shfl_xor(h, 2);
    h += __shfl_xor(h, 4);

    if (jc == 0) {
      const float sg = __builtin_amdgcn_rcpf(1.0f + __expf(-h));
      out[((size_t)t * BATCH + b) * NST + i] = h * h * sg;
    }
  }
#undef LD_STEP

  float4 o0 = {s[0], s[1], s[2], s[3]};
  float4 o1 = {s[4], s[5], s[6], s[7]};
  *(float4*)(Sout + ((size_t)b * NST + i) * NST + j0) = o0;
  *(float4*)(Sout + ((size_t)b * NST + i) * NST + j0 + 4) = o1;
}

extern "C" void kernel_launch(void* const* d_in, const int* in_sizes, int n_in,
                              void* d_out, int out_size, void* d_ws, size_t ws_size,
                              hipStream_t stream) {
  const float* x  = (const float*)d_in[0];
  const float* S0 = (const float*)d_in[1];
  const float* Wk = (const float*)d_in[2];
  const float* Wv = (const float*)d_in[3];
  const float* Wq = (const float*)d_in[4];
  const float* Wa = (const float*)d_in[5];
  const float* da = (const float*)d_in[6];
  const float* ba = (const float*)d_in[7];

  float* out  = (float*)d_out;                         // [T,B,64]
  float* Sout = out + (size_t)T_STEPS * BATCH * NST;   // [B,64,64]
  float* proj = (float*)d_ws;                          // [16384][256] = 16 MB

  dim3 ggrid(16384 / 128, 4);
  proj_gemm<<<ggrid, 128, 0, stream>>>(x, Wk, Wv, Wq, Wa, proj);
  scan_kernel<<<2 * BATCH, 256, 0, stream>>>(proj, S0, da, ba, out, Sout);
}

// Round 3
// 317.321 us; speedup vs baseline: 1.5875x; 1.5875x over previous
//
#include <hip/hip_runtime.h>
#include <hip/hip_bf16.h>

#define T_STEPS 512
#define BATCH 32
#define NST 64
#define DIM 1024

typedef _Float16 f16x8 __attribute__((ext_vector_type(8)));
typedef _Float16 f16x4 __attribute__((ext_vector_type(4)));
typedef _Float16 f16x2 __attribute__((ext_vector_type(2)));
typedef float f32x4 __attribute__((ext_vector_type(4)));

// ---------------- W concat + fp16 convert ----------------
// Wc[256][1024] fp16, row order [Wk | Wq | Wv | Wa] (k,q adjacent for the scan).
__global__ __launch_bounds__(256) void wconv(
    const float* __restrict__ Wk, const float* __restrict__ Wv,
    const float* __restrict__ Wq, const float* __restrict__ Wa,
    _Float16* __restrict__ Wc) {
  const int n = blockIdx.x;
  const int g = n >> 6, r = n & 63;
  const float* W = (g == 0) ? Wk : (g == 1) ? Wq : (g == 2) ? Wv : Wa;
  float4 v = *(const float4*)(W + (size_t)r * DIM + threadIdx.x * 4);
  f16x4 h = {(_Float16)v.x, (_Float16)v.y, (_Float16)v.z, (_Float16)v.w};
  *(f16x4*)(Wc + (size_t)n * DIM + threadIdx.x * 4) = h;
}

// ---------------- Projection GEMM via f16 MFMA ----------------
// projh[m][256] fp16, m = t*32+b; cols [k(64) q(64) v(64) ax(64)].
// Block: 64m x 256n, BK=32, 256 threads = 4 waves (2x2), wave tile 32m x 128n.
// A staged fp32->fp16 on the fly; LDS row stride 40 halves (80 B): 16B-aligned,
// <=2-way bank conflicts (free per m136).
__global__ __launch_bounds__(256, 1) void proj_gemm(
    const float* __restrict__ x, const _Float16* __restrict__ Wc,
    _Float16* __restrict__ projh) {
  const int m0 = blockIdx.x * 64;
  const int tid = threadIdx.x;
  const int r4 = tid >> 2;          // 0..63
  const int c8 = (tid & 3) * 8;     // k-chunk of 8

  __shared__ __align__(16) _Float16 Al[64 * 40];
  __shared__ __align__(16) _Float16 Bl[256 * 40];

  f32x4 acc[2][8];
#pragma unroll
  for (int mi = 0; mi < 2; ++mi)
#pragma unroll
    for (int ni = 0; ni < 8; ++ni) acc[mi][ni] = (f32x4){0.f, 0.f, 0.f, 0.f};

  float4 ax0, ax1;
  f16x8 bw[4];
#define GLOAD(k0)                                                              \
  {                                                                            \
    const float* xr = x + (size_t)(m0 + r4) * DIM + (k0) + c8;                 \
    ax0 = *(const float4*)xr;                                                  \
    ax1 = *(const float4*)(xr + 4);                                            \
    _Pragma("unroll") for (int pp = 0; pp < 4; ++pp)                           \
        bw[pp] = *(const f16x8*)(Wc + (size_t)(pp * 64 + r4) * DIM + (k0) + c8); \
  }

  const int lane = tid & 63, wv = tid >> 6;
  const int wm = wv >> 1, wn = wv & 1;
  const int fm = lane & 15, fq = lane >> 4;

  GLOAD(0);
  for (int kt = 0; kt < 32; ++kt) {
    __syncthreads();  // previous tile's frag reads complete
    f16x8 ah;
    ah[0] = (_Float16)ax0.x; ah[1] = (_Float16)ax0.y;
    ah[2] = (_Float16)ax0.z; ah[3] = (_Float16)ax0.w;
    ah[4] = (_Float16)ax1.x; ah[5] = (_Float16)ax1.y;
    ah[6] = (_Float16)ax1.z; ah[7] = (_Float16)ax1.w;
    *(f16x8*)&Al[r4 * 40 + c8] = ah;
#pragma unroll
    for (int pp = 0; pp < 4; ++pp)
      *(f16x8*)&Bl[(pp * 64 + r4) * 40 + c8] = bw[pp];
    __syncthreads();
    if (kt + 1 < 32) GLOAD((kt + 1) * 32);

    f16x8 afr[2], bfr[8];
#pragma unroll
    for (int mi = 0; mi < 2; ++mi)
      afr[mi] = *(const f16x8*)&Al[(wm * 32 + mi * 16 + fm) * 40 + fq * 8];
#pragma unroll
    for (int ni = 0; ni < 8; ++ni)
      bfr[ni] = *(const f16x8*)&Bl[(wn * 128 + ni * 16 + fm) * 40 + fq * 8];
#pragma unroll
    for (int mi = 0; mi < 2; ++mi)
#pragma unroll
      for (int ni = 0; ni < 8; ++ni)
        acc[mi][ni] =
            __builtin_amdgcn_mfma_f32_16x16x32_f16(afr[mi], bfr[ni], acc[mi][ni], 0, 0, 0);
  }
#undef GLOAD

  // C/D layout: col = lane&15, row = (lane>>4)*4 + reg  [m89-verified]
#pragma unroll
  for (int mi = 0; mi < 2; ++mi)
#pragma unroll
    for (int ni = 0; ni < 8; ++ni)
#pragma unroll
      for (int r = 0; r < 4; ++r) {
        int grow = m0 + wm * 32 + mi * 16 + fq * 4 + r;
        int gcol = wn * 128 + ni * 16 + fm;
        projh[(size_t)grow * 256 + gcol] = (_Float16)acc[mi][ni][r];
      }
}

// ---------------- Sequential scan ----------------
// 32 blocks (one per batch) x 256 threads. Thread owns rows {2rp, 2rp+1},
// cols [jc*8 .. jc*8+7] of S. jc sits on tid bits {0,1,3} so the 8-lane
// all-reduce is xor1 (quad_perm 0xB1) + xor2 (0x4E) + xor8 (row_ror:8) — all
// DPP (VALU latency), no DS-pipe shuffles. proj staged through a 2-chunk LDS
// ring (8 steps/chunk), global loads issued one full chunk ahead.
__device__ __forceinline__ float red8(float x) {
  int v = __builtin_amdgcn_update_dpp(0, __float_as_int(x), 0xB1, 0xF, 0xF, true);
  x += __int_as_float(v);
  v = __builtin_amdgcn_update_dpp(0, __float_as_int(x), 0x4E, 0xF, 0xF, true);
  x += __int_as_float(v);
  v = __builtin_amdgcn_update_dpp(0, __float_as_int(x), 0x128, 0xF, 0xF, true);
  x += __int_as_float(v);
  return x;
}

__global__ __launch_bounds__(256) void scan_kernel(
    const _Float16* __restrict__ projh, const float* __restrict__ S0,
    const float* __restrict__ d_alpha, const float* __restrict__ b_alpha,
    float* __restrict__ out, float* __restrict__ Sout) {
  const int b = blockIdx.x;
  const int tid = threadIdx.x;
  const int jc = (tid & 3) | ((tid >> 1) & 4);
  const int rp = ((tid >> 2) & 1) | ((tid >> 3) & 0x1E);
  const int j0 = jc * 8;
  const int r0 = rp * 2;

  __shared__ __align__(16) _Float16 lbuf[2 * 2048];  // 2 chunks x 8 steps x 256

  float s0[8], s1[8];
  {
    const float* Sb = S0 + ((size_t)b * NST + r0) * NST + j0;
    float4 t0 = *(const float4*)(Sb);
    float4 t1 = *(const float4*)(Sb + 4);
    float4 t2 = *(const float4*)(Sb + NST);
    float4 t3 = *(const float4*)(Sb + NST + 4);
    s0[0] = t0.x; s0[1] = t0.y; s0[2] = t0.z; s0[3] = t0.w;
    s0[4] = t1.x; s0[5] = t1.y; s0[6] = t1.z; s0[7] = t1.w;
    s1[0] = t2.x; s1[1] = t2.y; s1[2] = t2.z; s1[3] = t2.w;
    s1[4] = t3.x; s1[5] = t3.y; s1[6] = t3.z; s1[7] = t3.w;
  }
  const float2 dav = *(const float2*)(d_alpha + r0);
  const float2 bav = *(const float2*)(b_alpha + r0);

  const _Float16* gp = projh + (size_t)b * 256;
  const int lidx = (tid >> 5) * 256 + (tid & 31) * 8;
#define GADDR(c) (gp + (size_t)((c)*8 + (tid >> 5)) * (BATCH * 256) + (tid & 31) * 8)

  float4 rA;
  rA = *(const float4*)GADDR(0); *(float4*)(lbuf + lidx) = rA;
  rA = *(const float4*)GADDR(1); *(float4*)(lbuf + 2048 + lidx) = rA;
  rA = *(const float4*)GADDR(2);
  __syncthreads();

  f16x8 kf[2], qf[2];
  f16x2 vf[2], af[2];
#define PREF(tn)                                                         \
  {                                                                      \
    const int pp = (tn)&1;                                               \
    const _Float16* Pn = lbuf + (((tn) >> 3) & 1) * 2048 + ((tn)&7) * 256; \
    kf[pp] = *(const f16x8*)(Pn + j0);                                   \
    qf[pp] = *(const f16x8*)(Pn + 64 + j0);                              \
    vf[pp] = *(const f16x2*)(Pn + 128 + r0);                             \
    af[pp] = *(const f16x2*)(Pn + 192 + r0);                             \
  }

  PREF(0);
  for (int c = 0; c < 64; ++c) {
#pragma unroll
    for (int si = 0; si < 8; ++si) {
      const int t = c * 8 + si;
      const int p = t & 1;
      if (t + 1 < T_STEPS) PREF(t + 1);

      float kv[8], qv[8];
#pragma unroll
      for (int xx = 0; xx < 8; ++xx) {
        kv[xx] = (float)kf[p][xx];
        qv[xx] = (float)qf[p][xx];
      }
      const float vi0 = (float)vf[p][0], vi1 = (float)vf[p][1];
      const float axv0 = (float)af[p][0], axv1 = (float)af[p][1];

      // retrieved = S[row,:] . k  (8 owned + all-reduce over 8 jc lanes)
      float pa = fmaf(s0[0], kv[0], s0[1] * kv[1]);
      float pb = fmaf(s0[2], kv[2], s0[3] * kv[3]);
      float pc = fmaf(s0[4], kv[4], s0[5] * kv[5]);
      float pd = fmaf(s0[6], kv[6], s0[7] * kv[7]);
      float rr0 = red8((pa + pb) + (pc + pd));
      pa = fmaf(s1[0], kv[0], s1[1] * kv[1]);
      pb = fmaf(s1[2], kv[2], s1[3] * kv[3]);
      pc = fmaf(s1[4], kv[4], s1[5] * kv[5]);
      pd = fmaf(s1[6], kv[6], s1[7] * kv[7]);
      float rr1 = red8((pa + pb) + (pc + pd));

      const float z0 = fmaf(dav.x, rr0, axv0 + bav.x);
      const float z1 = fmaf(dav.y, rr1, axv1 + bav.y);
      // alpha = sigmoid(z); (1-alpha) = sigmoid(-z)  (inf-safe both tails)
      const float al0 = __builtin_amdgcn_rcpf(1.f + __expf(-z0));
      const float al1 = __builtin_amdgcn_rcpf(1.f + __expf(-z1));
      const float cc0 = vi0 * __builtin_amdgcn_rcpf(1.f + __expf(z0));
      const float cc1 = vi1 * __builtin_amdgcn_rcpf(1.f + __expf(z1));

      // S = al*S + cc*k ; h = S_new . q
      float h0a = 0.f, h0b = 0.f, h1a = 0.f, h1b = 0.f;
#pragma unroll
      for (int xx = 0; xx < 4; ++xx) {
        s0[xx] = fmaf(al0, s0[xx], cc0 * kv[xx]);
        s0[xx + 4] = fmaf(al0, s0[xx + 4], cc0 * kv[xx + 4]);
        s1[xx] = fmaf(al1, s1[xx], cc1 * kv[xx]);
        s1[xx + 4] = fmaf(al1, s1[xx + 4], cc1 * kv[xx + 4]);
        h0a = fmaf(s0[xx], qv[xx], h0a);
        h0b = fmaf(s0[xx + 4], qv[xx + 4], h0b);
        h1a = fmaf(s1[xx], qv[xx], h1a);
        h1b = fmaf(s1[xx + 4], qv[xx + 4], h1b);
      }
      const float h0 = red8(h0a + h0b);
      const float h1 = red8(h1a + h1b);

      if (jc == 0) {
        const float sg0 = __builtin_amdgcn_rcpf(1.f + __expf(-h0));
        const float sg1 = __builtin_amdgcn_rcpf(1.f + __expf(-h1));
        float2 o = {h0 * h0 * sg0, h1 * h1 * sg1};
        *(float2*)(out + ((size_t)t * BATCH + b) * NST + r0) = o;
      }
    }
    if (c + 2 < 64) {
      __syncthreads();  // all reads of buf[c&1] done
      *(float4*)(lbuf + (c & 1) * 2048 + lidx) = rA;  // chunk c+2
      if (c + 3 < 64) rA = *(const float4*)GADDR(c + 3);
      __syncthreads();  // store visible before chunk c+2 is read
    }
  }
#undef PREF
#undef GADDR

  float* So = Sout + ((size_t)b * NST + r0) * NST + j0;
  float4 o0 = {s0[0], s0[1], s0[2], s0[3]};
  float4 o1 = {s0[4], s0[5], s0[6], s0[7]};
  float4 o2 = {s1[0], s1[1], s1[2], s1[3]};
  float4 o3 = {s1[4], s1[5], s1[6], s1[7]};
  *(float4*)(So) = o0;
  *(float4*)(So + 4) = o1;
  *(float4*)(So + NST) = o2;
  *(float4*)(So + NST + 4) = o3;
}

extern "C" void kernel_launch(void* const* d_in, const int* in_sizes, int n_in,
                              void* d_out, int out_size, void* d_ws, size_t ws_size,
                              hipStream_t stream) {
  const float* x  = (const float*)d_in[0];
  const float* S0 = (const float*)d_in[1];
  const float* Wk = (const float*)d_in[2];
  const float* Wv = (const float*)d_in[3];
  const float* Wq = (const float*)d_in[4];
  const float* Wa = (const float*)d_in[5];
  const float* da = (const float*)d_in[6];
  const float* ba = (const float*)d_in[7];

  float* out  = (float*)d_out;                        // [T,B,64]
  float* Sout = out + (size_t)T_STEPS * BATCH * NST;  // [B,64,64]
  _Float16* projh = (_Float16*)d_ws;                  // [16384][256] fp16 = 8 MB
  _Float16* Wc = (_Float16*)((char*)d_ws + (size_t)16384 * 256 * 2);  // 512 KB

  wconv<<<256, 256, 0, stream>>>(Wk, Wv, Wq, Wa, Wc);
  proj_gemm<<<16384 / 64, 256, 0, stream>>>(x, Wc, projh);
  scan_kernel<<<BATCH, 256, 0, stream>>>(projh, S0, da, ba, out, Sout);
}

// Round 4
// 226.333 us; speedup vs baseline: 2.2257x; 1.4020x over previous
//
#include <hip/hip_runtime.h>
#include <hip/hip_bf16.h>

#define T_STEPS 512
#define BATCH 32
#define NST 64
#define DIM 1024

typedef _Float16 f16x8 __attribute__((ext_vector_type(8)));
typedef _Float16 f16x4 __attribute__((ext_vector_type(4)));
typedef _Float16 f16x2 __attribute__((ext_vector_type(2)));
typedef float f32x4 __attribute__((ext_vector_type(4)));

__device__ __forceinline__ void gl_lds16(const void* g, void* l) {
  __builtin_amdgcn_global_load_lds(
      (const __attribute__((address_space(1))) void*)g,
      (__attribute__((address_space(3))) void*)l, 16, 0, 0);
}

// ---------------- W concat + fp16 convert ----------------
// Wc[256][1024] fp16, row order [Wk | Wq | Wv | Wa].
__global__ __launch_bounds__(256) void wconv(
    const float* __restrict__ Wk, const float* __restrict__ Wv,
    const float* __restrict__ Wq, const float* __restrict__ Wa,
    _Float16* __restrict__ Wc) {
  const int n = blockIdx.x;
  const int g = n >> 6, r = n & 63;
  const float* W = (g == 0) ? Wk : (g == 1) ? Wq : (g == 2) ? Wv : Wa;
  float4 v = *(const float4*)(W + (size_t)r * DIM + threadIdx.x * 4);
  f16x4 h = {(_Float16)v.x, (_Float16)v.y, (_Float16)v.z, (_Float16)v.w};
  *(f16x4*)(Wc + (size_t)n * DIM + threadIdx.x * 4) = h;
}

// ---------------- Projection GEMM (m97-style) ----------------
// projh[m][256] fp16, cols [k(64) | q(64) | v,ax interleaved(128)].
// Block 64m x 128n, BK=32, 4 waves (2x2), wave tile 32m x 64n.
// B staged via global_load_lds (16B) into double buffer, XOR-swizzled k-chunks;
// A (fp32->fp16) through padded LDS (stride 40 halves).
__global__ __launch_bounds__(256) void proj_gemm(
    const float* __restrict__ x, const _Float16* __restrict__ Wc,
    _Float16* __restrict__ projh) {
  const int m0 = blockIdx.x * 64;
  const int n0 = blockIdx.y * 128;
  const int tid = threadIdx.x;
  const int lane = tid & 63, wv = tid >> 6;
  const int wm = wv >> 1, wn = wv & 1;
  const int fm = lane & 15, fq = lane >> 4;

  __shared__ __align__(16) _Float16 Al[64 * 40];
  __shared__ __align__(16) _Float16 Bl[2][128 * 32];

  // B staging: wave wv covers rows [wv*32, wv*32+32), 2 instrs of 16 rows.
  // LDS dest = wave-uniform base + lane*16B; logical k-chunk XOR-swizzled so
  // frag reads are bank-quad balanced.
  const int bro = wv * 32 + (lane >> 2);
  const int bchunk = (lane & 3) ^ ((lane >> 3) & 3);
  const _Float16* gB = Wc + (size_t)(n0 + bro) * DIM + bchunk * 8;
  const int bl_off = bro * 32 + (lane & 3) * 8;

  // A staging: thread loads 8 floats of one x row.
  const int arow = tid >> 2;
  const int acol = (tid & 3) * 8;
  const float* gA = x + (size_t)(m0 + arow) * DIM + acol;

  f32x4 acc[2][4];
#pragma unroll
  for (int mi = 0; mi < 2; ++mi)
#pragma unroll
    for (int ni = 0; ni < 4; ++ni) acc[mi][ni] = (f32x4){0.f, 0.f, 0.f, 0.f};

#define STAGE_B(buf, k0)                                       \
  {                                                            \
    _Pragma("unroll") for (int j = 0; j < 2; ++j)              \
        gl_lds16(gB + (size_t)j * 16 * DIM + (k0),             \
                 &Bl[buf][bl_off + j * 16 * 32]);              \
  }
  float4 xa, xb;
#define LOAD_A(k0)                          \
  {                                         \
    xa = *(const float4*)(gA + (k0));       \
    xb = *(const float4*)(gA + (k0) + 4);   \
  }

  STAGE_B(0, 0);
  LOAD_A(0);
  const int aswz = (fq ^ ((fm >> 1) & 3)) * 8;
  for (int kt = 0; kt < 32; ++kt) {
    __syncthreads();  // drains B buf[kt&1] (vmcnt) + prior readers done
    f16x8 ah;
    ah[0] = (_Float16)xa.x; ah[1] = (_Float16)xa.y;
    ah[2] = (_Float16)xa.z; ah[3] = (_Float16)xa.w;
    ah[4] = (_Float16)xb.x; ah[5] = (_Float16)xb.y;
    ah[6] = (_Float16)xb.z; ah[7] = (_Float16)xb.w;
    *(f16x8*)&Al[arow * 40 + acol] = ah;
    __syncthreads();  // A visible
    if (kt + 1 < 32) {
      LOAD_A(kt * 32 + 32);
      STAGE_B((kt + 1) & 1, kt * 32 + 32);
    }
    f16x8 afr[2], bfr[4];
#pragma unroll
    for (int mi = 0; mi < 2; ++mi)
      afr[mi] = *(const f16x8*)&Al[(wm * 32 + mi * 16 + fm) * 40 + fq * 8];
#pragma unroll
    for (int ni = 0; ni < 4; ++ni) {
      const int row = wn * 64 + ni * 16 + fm;
      bfr[ni] = *(const f16x8*)&Bl[kt & 1][row * 32 + aswz];
    }
#pragma unroll
    for (int mi = 0; mi < 2; ++mi)
#pragma unroll
      for (int ni = 0; ni < 4; ++ni)
        acc[mi][ni] =
            __builtin_amdgcn_mfma_f32_16x16x32_f16(afr[mi], bfr[ni], acc[mi][ni], 0, 0, 0);
  }
#undef STAGE_B
#undef LOAD_A

  // C/D: col = lane&15, row = (lane>>4)*4 + reg. Remap cols: v,ax interleaved.
#pragma unroll
  for (int mi = 0; mi < 2; ++mi)
#pragma unroll
    for (int ni = 0; ni < 4; ++ni) {
      const int gcol = n0 + wn * 64 + ni * 16 + fm;
      const int pcol = gcol < 128 ? gcol
                     : (gcol < 192 ? 128 + 2 * (gcol - 128) : 129 + 2 * (gcol - 192));
#pragma unroll
      for (int r = 0; r < 4; ++r) {
        const int grow = m0 + wm * 32 + mi * 16 + fq * 4 + r;
        projh[(size_t)grow * 256 + pcol] = (_Float16)acc[mi][ni][r];
      }
    }
}

// ---------------- Sequential scan ----------------
// 128 blocks = (b, 16-row group), 256 threads = 16 rows x 16 lanes.
// Thread (r, c) owns S[b][r][4c..4c+3] in registers. 16-lane all-reduce via
// DPP: quad_perm xor1, xor2, row_ror:4, row_ror:8 (no DS pipe).
// proj staged through 2-chunk LDS ring (8 steps/chunk), loads 1 chunk ahead.
__device__ __forceinline__ float red16(float x) {
  int v = __builtin_amdgcn_update_dpp(0, __float_as_int(x), 0xB1, 0xF, 0xF, true);
  x += __int_as_float(v);
  v = __builtin_amdgcn_update_dpp(0, __float_as_int(x), 0x4E, 0xF, 0xF, true);
  x += __int_as_float(v);
  v = __builtin_amdgcn_update_dpp(0, __float_as_int(x), 0x124, 0xF, 0xF, true);
  x += __int_as_float(v);
  v = __builtin_amdgcn_update_dpp(0, __float_as_int(x), 0x128, 0xF, 0xF, true);
  x += __int_as_float(v);
  return x;
}

__global__ __launch_bounds__(256) void scan_kernel(
    const _Float16* __restrict__ projh, const float* __restrict__ S0,
    const float* __restrict__ d_alpha, const float* __restrict__ b_alpha,
    float* __restrict__ out, float* __restrict__ Sout) {
  const int b = blockIdx.x >> 2;
  const int rg = blockIdx.x & 3;
  const int tid = threadIdx.x;
  const int c = tid & 15;          // column lane
  const int r = rg * 16 + (tid >> 4);
  const int j0 = c * 4;

  __shared__ __align__(16) _Float16 lbuf[2 * 2048];  // 2 chunks x 8 steps x 256

  float s[4];
  {
    float4 v = *(const float4*)(S0 + ((size_t)b * NST + r) * NST + j0);
    s[0] = v.x; s[1] = v.y; s[2] = v.z; s[3] = v.w;
  }
  const float da = d_alpha[r];
  const float ba = b_alpha[r];

  const _Float16* gp = projh + (size_t)b * 256;
  const int lidx = (tid >> 5) * 256 + (tid & 31) * 8;
#define GADDR(ch) (gp + (size_t)((ch) * 8 + (tid >> 5)) * (BATCH * 256) + (tid & 31) * 8)

  float4 rA;
  rA = *(const float4*)GADDR(0); *(float4*)(lbuf + lidx) = rA;
  rA = *(const float4*)GADDR(1); *(float4*)(lbuf + 2048 + lidx) = rA;
  rA = *(const float4*)GADDR(2);
  __syncthreads();

  f16x4 kf[2], qf[2];
  f16x2 vaf[2];
#define PREF(tn)                                                           \
  {                                                                        \
    const int pp = (tn)&1;                                                 \
    const _Float16* Pn = lbuf + (((tn) >> 3) & 1) * 2048 + ((tn)&7) * 256; \
    kf[pp] = *(const f16x4*)(Pn + j0);                                     \
    qf[pp] = *(const f16x4*)(Pn + 64 + j0);                                \
    vaf[pp] = *(const f16x2*)(Pn + 128 + 2 * r);                           \
  }

  PREF(0);
  for (int ch = 0; ch < 64; ++ch) {
#pragma unroll
    for (int si = 0; si < 8; ++si) {
      const int t = ch * 8 + si;
      const int p = t & 1;
      if (t + 1 < T_STEPS) PREF(t + 1);

      const float k0 = (float)kf[p][0], k1 = (float)kf[p][1];
      const float k2 = (float)kf[p][2], k3 = (float)kf[p][3];
      const float q0 = (float)qf[p][0], q1 = (float)qf[p][1];
      const float q2 = (float)qf[p][2], q3 = (float)qf[p][3];
      const float vi = (float)vaf[p][0];
      const float axv = (float)vaf[p][1];

      // retrieved = S[r,:] . k (4 owned + 16-lane allreduce)
      const float pa = fmaf(s[0], k0, s[1] * k1);
      const float pb = fmaf(s[2], k2, s[3] * k3);
      const float rr = red16(pa + pb);

      float z = fmaf(da, rr, axv + ba);
      z = fminf(fmaxf(z, -30.f), 30.f);  // inf-safe (numerically exact in range)
      const float e = __expf(-z);
      const float al = __builtin_amdgcn_rcpf(1.f + e);  // sigmoid(z)
      const float cc = (e * vi) * al;                   // (1-al)*v

      // S = al*S + cc*k ; h = S_new . q
      s[0] = fmaf(al, s[0], cc * k0);
      s[1] = fmaf(al, s[1], cc * k1);
      s[2] = fmaf(al, s[2], cc * k2);
      s[3] = fmaf(al, s[3], cc * k3);
      const float ha = fmaf(s[0], q0, s[1] * q1);
      const float hb = fmaf(s[2], q2, s[3] * q3);
      const float h = red16(ha + hb);

      if (c == 0) {
        const float sg = __builtin_amdgcn_rcpf(1.f + __expf(-h));
        out[((size_t)t * BATCH + b) * NST + r] = h * h * sg;
      }
    }
    if (ch + 2 < 64) {
      __syncthreads();                                 // reads of buf[ch&1] done
      *(float4*)(lbuf + (ch & 1) * 2048 + lidx) = rA;  // stage chunk ch+2
      if (ch + 3 < 64) rA = *(const float4*)GADDR(ch + 3);
      __syncthreads();                                 // visible before read
    }
  }
#undef PREF
#undef GADDR

  float4 o = {s[0], s[1], s[2], s[3]};
  *(float4*)(Sout + ((size_t)b * NST + r) * NST + j0) = o;
}

extern "C" void kernel_launch(void* const* d_in, const int* in_sizes, int n_in,
                              void* d_out, int out_size, void* d_ws, size_t ws_size,
                              hipStream_t stream) {
  const float* x  = (const float*)d_in[0];
  const float* S0 = (const float*)d_in[1];
  const float* Wk = (const float*)d_in[2];
  const float* Wv = (const float*)d_in[3];
  const float* Wq = (const float*)d_in[4];
  const float* Wa = (const float*)d_in[5];
  const float* da = (const float*)d_in[6];
  const float* ba = (const float*)d_in[7];

  float* out  = (float*)d_out;                        // [T,B,64]
  float* Sout = out + (size_t)T_STEPS * BATCH * NST;  // [B,64,64]
  _Float16* projh = (_Float16*)d_ws;                  // [16384][256] fp16 = 8 MB
  _Float16* Wc = (_Float16*)((char*)d_ws + (size_t)16384 * 256 * 2);  // 512 KB

  wconv<<<256, 256, 0, stream>>>(Wk, Wv, Wq, Wa, Wc);
  dim3 ggrid(16384 / 64, 2);
  proj_gemm<<<ggrid, 256, 0, stream>>>(x, Wc, projh);
  scan_kernel<<<4 * BATCH, 256, 0, stream>>>(projh, S0, da, ba, out, Sout);
}